// Round 1
// baseline (679.914 us; speedup 1.0000x reference)
//
#include <hip/hip_runtime.h>

// PairwiseMLPLinkPredictor on MI355X (gfx950)
// feats = bf16(x[u]) * bf16(x[v]);  h1 = relu(feats@W1+b1);  h2 = relu(h1@W2+b2);
// out = h2@W3 + b3.   GEMM1/2 via v_mfma_f32_16x16x32_bf16, layer 3 fused in epilogue.

typedef __attribute__((ext_vector_type(8))) short short8;   // 8 bf16 = 4 VGPRs
typedef __attribute__((ext_vector_type(4))) float floatx4;  // MFMA C/D frag

#define MT 128        // pairs per block
#define NTHREADS 512  // 8 waves

__device__ __forceinline__ unsigned short f2bf(float f) {
  union { float f; unsigned u; } a; a.f = f;
  unsigned r = a.u + 0x7FFFu + ((a.u >> 16) & 1u);   // round-to-nearest-even
  return (unsigned short)(r >> 16);
}

// ---------- prologue: x -> bf16 table ----------
__global__ void cast_x_kernel(const float* __restrict__ x, unsigned short* __restrict__ xb, int n4) {
  int i = blockIdx.x * blockDim.x + threadIdx.x;
  if (i >= n4) return;
  float4 v = ((const float4*)x)[i];
  ushort4 o;
  o.x = f2bf(v.x); o.y = f2bf(v.y); o.z = f2bf(v.z); o.w = f2bf(v.w);
  ((ushort4*)xb)[i] = o;
}

// ---------- prologue: W1 [256,256] / W2 [256,128] -> bf16, transposed to [n][k] ----------
__global__ void prep_w_kernel(const float* __restrict__ W1, const float* __restrict__ W2,
                              unsigned short* __restrict__ w1t, unsigned short* __restrict__ w2t) {
  int i = blockIdx.x * blockDim.x + threadIdx.x;
  if (i < 256 * 256) {
    int k = i >> 8, n = i & 255;
    w1t[n * 256 + k] = f2bf(W1[k * 256 + n]);
  } else {
    int j = i - 256 * 256;
    if (j < 128 * 256) {
      int k = j >> 7, n = j & 127;
      w2t[n * 256 + k] = f2bf(W2[k * 128 + n]);
    }
  }
}

// ---------- fused pairwise MLP ----------
// LDS buf0: 128 rows x 256 bf16 = 64 KB exactly (2 blocks/CU).
// 16B chunks of each row are XOR-swizzled by (row & 15): conflict-free ds_read_b128
// A-fragment loads without padding (padding would break the 64 KB static limit).
__global__ __launch_bounds__(NTHREADS, 4) void mlp_kernel(
    const unsigned short* __restrict__ xb,
    const unsigned short* __restrict__ w1t,
    const unsigned short* __restrict__ w2t,
    const float* __restrict__ b1,
    const float* __restrict__ b2,
    const float* __restrict__ w3,
    const float* __restrict__ b3,
    const int* __restrict__ ep,
    float* __restrict__ out,
    int E)
{
  __shared__ __align__(16) unsigned short buf0[MT * 256];  // 65536 B

  const int tid  = threadIdx.x;
  const int wv   = tid >> 6;
  const int lane = tid & 63;
  const int q    = lane >> 4;     // quad-row 0..3
  const int r16  = lane & 15;
  const int row0 = blockIdx.x * MT;
  char* const ldsb = (char*)buf0;

  // ---- gather + elementwise product -> feats in LDS ----
  {
    const int c    = tid & 31;    // 16B chunk (32 per 512B row)
    const int mrow = tid >> 5;    // 0..15
    #pragma unroll
    for (int pass = 0; pass < 8; ++pass) {
      int m = pass * 16 + mrow;
      int g = row0 + m;
      int u = 0, v = 0;
      if (g < E) { u = ep[2 * g]; v = ep[2 * g + 1]; }
      uint4 a = *(const uint4*)(xb + ((size_t)u << 8) + (c << 3));
      uint4 b = *(const uint4*)(xb + ((size_t)v << 8) + (c << 3));
      const unsigned* au = &a.x;
      const unsigned* bu = &b.x;
      uint4 pv;
      unsigned* po = &pv.x;
      #pragma unroll
      for (int t = 0; t < 4; ++t) {
        unsigned ua = au[t], ub = bu[t];
        float lo = __uint_as_float(ua << 16)          * __uint_as_float(ub << 16);
        float hi = __uint_as_float(ua & 0xFFFF0000u) * __uint_as_float(ub & 0xFFFF0000u);
        po[t] = (unsigned)f2bf(lo) | ((unsigned)f2bf(hi) << 16);
      }
      int cp = c ^ (m & 15);                       // swizzle
      *(uint4*)(ldsb + m * 512 + (cp << 4)) = pv;
    }
  }
  __syncthreads();

  const int mg = wv >> 2;                 // 0..1: 64-row slab
  const int ng = wv & 3;                  // 0..3: 64-col slab (GEMM1) / 32-col (GEMM2)
  const int swz16 = (q ^ r16) << 4;       // A-frag chunk swizzle, byte units

  // ---- GEMM1: h1 = relu(feats @ W1 + b1), acc 64x64 per wave ----
  floatx4 acc[4][4];
  #pragma unroll
  for (int i = 0; i < 4; ++i)
    #pragma unroll
    for (int j = 0; j < 4; ++j)
      acc[i][j] = (floatx4){0.f, 0.f, 0.f, 0.f};

  char* const arow = ldsb + (mg * 64 + r16) * 512;                       // A row base
  const unsigned short* const brow = w1t + (ng * 64 + r16) * 256 + q * 8; // B base (global, L2-hot)

  #pragma unroll
  for (int kt = 0; kt < 8; ++kt) {
    short8 av[4], bv[4];
    #pragma unroll
    for (int mt = 0; mt < 4; ++mt)
      av[mt] = *(const short8*)(arow + mt * (16 * 512) + ((kt << 6) ^ swz16));
    #pragma unroll
    for (int nt = 0; nt < 4; ++nt)
      bv[nt] = *(const short8*)(brow + nt * (16 * 256) + kt * 32);
    #pragma unroll
    for (int mt = 0; mt < 4; ++mt)
      #pragma unroll
      for (int nt = 0; nt < 4; ++nt)
        acc[mt][nt] = __builtin_amdgcn_mfma_f32_16x16x32_bf16(av[mt], bv[nt], acc[mt][nt], 0, 0, 0);
  }

  __syncthreads();   // all waves done reading feats

  // ---- writeback h1 (bias+relu, bf16) into buf0, swizzled ----
  {
    float bias1[4];
    #pragma unroll
    for (int nt = 0; nt < 4; ++nt) bias1[nt] = b1[ng * 64 + nt * 16 + r16];
    #pragma unroll
    for (int mt = 0; mt < 4; ++mt) {
      #pragma unroll
      for (int r = 0; r < 4; ++r) {
        int mlo = q * 4 + r;                      // m & 15  (C/D: row = 4*quad + reg)
        int m = mg * 64 + mt * 16 + mlo;
        char* rowp = ldsb + m * 512;
        #pragma unroll
        for (int nt = 0; nt < 4; ++nt) {
          int n = ng * 64 + nt * 16 + r16;        // C/D: col = lane&15
          float h = fmaxf(acc[mt][nt][r] + bias1[nt], 0.f);
          int ch = (n >> 3) ^ mlo;
          *(unsigned short*)(rowp + (ch << 4) + ((n & 7) << 1)) = f2bf(h);
        }
      }
    }
  }
  __syncthreads();

  // ---- GEMM2: h2 = relu(h1 @ W2 + b2), acc 64x32 per wave ----
  floatx4 acc2[4][2];
  #pragma unroll
  for (int i = 0; i < 4; ++i) {
    acc2[i][0] = (floatx4){0.f, 0.f, 0.f, 0.f};
    acc2[i][1] = (floatx4){0.f, 0.f, 0.f, 0.f};
  }
  const unsigned short* const b2row = w2t + (ng * 32 + r16) * 256 + q * 8;

  #pragma unroll
  for (int kt = 0; kt < 8; ++kt) {
    short8 av[4], bv[2];
    #pragma unroll
    for (int mt = 0; mt < 4; ++mt)
      av[mt] = *(const short8*)(arow + mt * (16 * 512) + ((kt << 6) ^ swz16));
    #pragma unroll
    for (int nt = 0; nt < 2; ++nt)
      bv[nt] = *(const short8*)(b2row + nt * (16 * 256) + kt * 32);
    #pragma unroll
    for (int mt = 0; mt < 4; ++mt)
      #pragma unroll
      for (int nt = 0; nt < 2; ++nt)
        acc2[mt][nt] = __builtin_amdgcn_mfma_f32_16x16x32_bf16(av[mt], bv[nt], acc2[mt][nt], 0, 0, 0);
  }

  __syncthreads();   // all reads of h1 done -> reuse buf0 head as score accumulator

  float* ss = (float*)buf0;
  if (tid < MT) ss[tid] = 0.f;
  __syncthreads();

  // ---- fused layer 3: scores[m] = sum_n relu(h2[m][n]) * W3[n]  (+b3) ----
  {
    float b2v[2], w3v[2];
    #pragma unroll
    for (int nt = 0; nt < 2; ++nt) {
      int n2 = ng * 32 + nt * 16 + r16;
      b2v[nt] = b2[n2];
      w3v[nt] = w3[n2];
    }
    #pragma unroll
    for (int mt = 0; mt < 4; ++mt) {
      #pragma unroll
      for (int r = 0; r < 4; ++r) {
        float p = 0.f;
        #pragma unroll
        for (int nt = 0; nt < 2; ++nt) {
          float h = fmaxf(acc2[mt][nt][r] + b2v[nt], 0.f);
          p += h * w3v[nt];
        }
        // reduce over the 16 lanes of this quad-row (masks <16 stay in-group)
        p += __shfl_xor(p, 1);
        p += __shfl_xor(p, 2);
        p += __shfl_xor(p, 4);
        p += __shfl_xor(p, 8);
        if (r16 == 0) atomicAdd(&ss[mg * 64 + mt * 16 + q * 4 + r], p);
      }
    }
  }
  __syncthreads();

  if (tid < MT) {
    int g = row0 + tid;
    if (g < E) out[g] = ss[tid] + b3[0];
  }
}

extern "C" void kernel_launch(void* const* d_in, const int* in_sizes, int n_in,
                              void* d_out, int out_size, void* d_ws, size_t ws_size,
                              hipStream_t stream) {
  const float* x  = (const float*)d_in[0];
  const float* W1 = (const float*)d_in[1];
  const float* b1 = (const float*)d_in[2];
  const float* W2 = (const float*)d_in[3];
  const float* b2 = (const float*)d_in[4];
  const float* W3 = (const float*)d_in[5];
  const float* b3 = (const float*)d_in[6];
  // d_in[7] = edge_index (unused by the reference computation)
  const int*   ep = (const int*)d_in[8];
  float* out = (float*)d_out;

  const int NX = in_sizes[0];        // 100000*256 = 25,600,000
  const int E  = in_sizes[8] / 2;    // 1,000,000

  // workspace layout: xb (NX bf16) | w1t (256*256 bf16) | w2t (128*256 bf16)  ~49 MB
  unsigned short* xb  = (unsigned short*)d_ws;
  unsigned short* w1t = (unsigned short*)((char*)d_ws + (size_t)NX * 2);
  unsigned short* w2t = w1t + 256 * 256;

  cast_x_kernel<<<(NX / 4 + 255) / 256, 256, 0, stream>>>(x, xb, NX / 4);
  prep_w_kernel<<<(256 * 256 + 128 * 256 + 255) / 256, 256, 0, stream>>>(W1, W2, w1t, w2t);
  mlp_kernel<<<(E + MT - 1) / MT, NTHREADS, 0, stream>>>(xb, w1t, w2t, b1, b2, W3, b3, ep, out, E);
}